// Round 9
// baseline (108.102 us; speedup 1.0000x reference)
//
#include <hip/hip_runtime.h>

#define BH  64
#define SEQ 4096
#define DH  64
#define NCHUNK 32
#define CROWS  (SEQ / NCHUNK)   // 128 rows per chunk
#define WROWS  (CROWS / 4)      // 32 rows per wave

// ---------------------------------------------------------------------------
// Kernel 1: partial kv = k^T v over a 128-row chunk. One (b,h,chunk)/block.
// 256 threads = 4 waves. NO barriers, NO LDS staging in the main loop:
// each wave independently streams its own 32-row stripe; each lane owns an
// 8(d) x 8(e) register tile (64 lanes cover 64x64). Per 2-row batch:
// 8 global float4 loads -> 128 FMA. Coalescer merges lane-duplicate k/v
// addresses (k: 256B/row/wave, v: 8 distinct 32B). Cross-wave partials
// reduced once through LDS at the end. __launch_bounds__(256,4): VGPR<=128
// -> 16 waves/CU; grid 2048 blocks = 8 blocks/CU available.
// ---------------------------------------------------------------------------
__global__ __launch_bounds__(256, 4) void kv_partial_kernel(
    const float* __restrict__ k, const float* __restrict__ v,
    float* __restrict__ partial) {
  const int t = threadIdx.x;
  const int bh = blockIdx.x >> 5;             // / NCHUNK
  const int chunk = blockIdx.x & (NCHUNK - 1);

  const int g   = t & 63;
  const int grp = t >> 6;
  const int d0 = (g & 7) * 8;
  const int e0 = (g >> 3) * 8;

  const size_t base = (size_t)bh * SEQ * DH + ((size_t)chunk * CROWS + grp * WROWS) * DH;
  const float* kw = k + base;
  const float* vw = v + base;

  __shared__ float smem[8192];   // used only for the final cross-wave reduce

  float acc[8][8];
#pragma unroll
  for (int i = 0; i < 8; ++i)
#pragma unroll
    for (int j = 0; j < 8; ++j) acc[i][j] = 0.f;

  for (int r0 = 0; r0 < WROWS; r0 += 2) {
    // issue both rows' loads up front (8 independent dwordx4)
    float4 ka0 = *(const float4*)(kw + (size_t)r0 * DH + d0);
    float4 ka1 = *(const float4*)(kw + (size_t)r0 * DH + d0 + 4);
    float4 va0 = *(const float4*)(vw + (size_t)r0 * DH + e0);
    float4 va1 = *(const float4*)(vw + (size_t)r0 * DH + e0 + 4);
    float4 kb0 = *(const float4*)(kw + (size_t)(r0 + 1) * DH + d0);
    float4 kb1 = *(const float4*)(kw + (size_t)(r0 + 1) * DH + d0 + 4);
    float4 vb0 = *(const float4*)(vw + (size_t)(r0 + 1) * DH + e0);
    float4 vb1 = *(const float4*)(vw + (size_t)(r0 + 1) * DH + e0 + 4);

    {
      float kk[8] = {ka0.x, ka0.y, ka0.z, ka0.w, ka1.x, ka1.y, ka1.z, ka1.w};
      float vv[8] = {va0.x, va0.y, va0.z, va0.w, va1.x, va1.y, va1.z, va1.w};
#pragma unroll
      for (int i = 0; i < 8; ++i)
#pragma unroll
        for (int j = 0; j < 8; ++j) acc[i][j] += kk[i] * vv[j];
    }
    {
      float kk[8] = {kb0.x, kb0.y, kb0.z, kb0.w, kb1.x, kb1.y, kb1.z, kb1.w};
      float vv[8] = {vb0.x, vb0.y, vb0.z, vb0.w, vb1.x, vb1.y, vb1.z, vb1.w};
#pragma unroll
      for (int i = 0; i < 8; ++i)
#pragma unroll
        for (int j = 0; j < 8; ++j) acc[i][j] += kk[i] * vv[j];
    }
  }

  // ---- cross-wave reduction through LDS (one-time) ----
  __syncthreads();
  if (grp >= 2) {
    float* reg = smem + (grp - 2) * 4096;
#pragma unroll
    for (int i = 0; i < 8; ++i) {
      float4 w0 = {acc[i][0], acc[i][1], acc[i][2], acc[i][3]};
      float4 w1 = {acc[i][4], acc[i][5], acc[i][6], acc[i][7]};
      *(float4*)&reg[(2 * i) * 256 + g * 4]     = w0;
      *(float4*)&reg[(2 * i + 1) * 256 + g * 4] = w1;
    }
  }
  __syncthreads();
  if (grp < 2) {
    const float* reg = smem + grp * 4096;
#pragma unroll
    for (int i = 0; i < 8; ++i) {
      float4 a = *(const float4*)&reg[(2 * i) * 256 + g * 4];
      float4 b = *(const float4*)&reg[(2 * i + 1) * 256 + g * 4];
      acc[i][0] += a.x; acc[i][1] += a.y; acc[i][2] += a.z; acc[i][3] += a.w;
      acc[i][4] += b.x; acc[i][5] += b.y; acc[i][6] += b.z; acc[i][7] += b.w;
    }
  }
  __syncthreads();
  if (grp == 1) {
#pragma unroll
    for (int i = 0; i < 8; ++i) {
      float4 w0 = {acc[i][0], acc[i][1], acc[i][2], acc[i][3]};
      float4 w1 = {acc[i][4], acc[i][5], acc[i][6], acc[i][7]};
      *(float4*)&smem[(2 * i) * 256 + g * 4]     = w0;
      *(float4*)&smem[(2 * i + 1) * 256 + g * 4] = w1;
    }
  }
  __syncthreads();
  if (grp == 0) {
#pragma unroll
    for (int i = 0; i < 8; ++i) {
      float4 a = *(const float4*)&smem[(2 * i) * 256 + g * 4];
      float4 b = *(const float4*)&smem[(2 * i + 1) * 256 + g * 4];
      acc[i][0] += a.x; acc[i][1] += a.y; acc[i][2] += a.z; acc[i][3] += a.w;
      acc[i][4] += b.x; acc[i][5] += b.y; acc[i][6] += b.z; acc[i][7] += b.w;
    }
    float* pb = partial + (size_t)blockIdx.x * (DH * DH);
#pragma unroll
    for (int i = 0; i < 8; ++i) {
      float4 w0 = {acc[i][0], acc[i][1], acc[i][2], acc[i][3]};
      float4 w1 = {acc[i][4], acc[i][5], acc[i][6], acc[i][7]};
      *(float4*)&pb[(d0 + i) * 64 + e0]     = w0;
      *(float4*)&pb[(d0 + i) * 64 + e0 + 4] = w1;
    }
  }
}

// ---------------------------------------------------------------------------
// Kernel 2: reduce partials -> kvf [BH][64*64]. 256 blocks x 256 threads
// covers 65536 float4 slots.
// ---------------------------------------------------------------------------
__global__ __launch_bounds__(256) void kv_reduce_kernel(
    const float* __restrict__ partial, float* __restrict__ kvf) {
  const int gid = blockIdx.x * 256 + threadIdx.x;
  const int bh = gid >> 10;
  const int idx = gid & 1023;
  float4 s = {0.f, 0.f, 0.f, 0.f};
  for (int c = 0; c < NCHUNK; ++c) {
    const float4* p = (const float4*)(partial + ((size_t)bh * NCHUNK + c) * (DH * DH));
    float4 x = p[idx];
    s.x += x.x; s.y += x.y; s.z += x.z; s.w += x.w;
  }
  ((float4*)kvf)[gid] = s;
}

// ---------------------------------------------------------------------------
// Kernel 3: out = q @ kv. Block = 64 q-rows. Thread = 1 row x 16 cols.
// Entire q row hoisted to registers up front; kv in LDS, broadcast reads.
// ---------------------------------------------------------------------------
__global__ __launch_bounds__(256) void out_kernel(
    const float* __restrict__ q, const float* __restrict__ kvf,
    float* __restrict__ out) {
  const int t = threadIdx.x;
  const int bh = blockIdx.x >> 6;
  const int rb = blockIdx.x & 63;
  const int row = rb * 64 + (t >> 2);
  const int c0 = (t & 3) * 16;

  __shared__ float kv_lds[64 * 64];

  const float4* gkv4 = (const float4*)(kvf + (size_t)bh * (DH * DH));
  float4* kv4 = (float4*)kv_lds;
#pragma unroll
  for (int j = 0; j < 4; ++j) kv4[t + j * 256] = gkv4[t + j * 256];

  const float* qrow = q + (size_t)bh * SEQ * DH + (size_t)row * DH;
  float4 qv[16];
#pragma unroll
  for (int i = 0; i < 16; ++i) qv[i] = *(const float4*)&qrow[i * 4];

  __syncthreads();

  float acc[16];
#pragma unroll
  for (int j = 0; j < 16; ++j) acc[j] = 0.f;

#pragma unroll
  for (int dc = 0; dc < 16; ++dc) {
    float qs[4] = {qv[dc].x, qv[dc].y, qv[dc].z, qv[dc].w};
#pragma unroll
    for (int dd = 0; dd < 4; ++dd) {
      const float* kr = &kv_lds[(dc * 4 + dd) * 64 + c0];
      float4 k0 = *(const float4*)&kr[0];
      float4 k1 = *(const float4*)&kr[4];
      float4 k2 = *(const float4*)&kr[8];
      float4 k3 = *(const float4*)&kr[12];
      const float qsv = qs[dd];
      acc[0]  += qsv * k0.x; acc[1]  += qsv * k0.y;
      acc[2]  += qsv * k0.z; acc[3]  += qsv * k0.w;
      acc[4]  += qsv * k1.x; acc[5]  += qsv * k1.y;
      acc[6]  += qsv * k1.z; acc[7]  += qsv * k1.w;
      acc[8]  += qsv * k2.x; acc[9]  += qsv * k2.y;
      acc[10] += qsv * k2.z; acc[11] += qsv * k2.w;
      acc[12] += qsv * k3.x; acc[13] += qsv * k3.y;
      acc[14] += qsv * k3.z; acc[15] += qsv * k3.w;
    }
  }

  float* ob = out + (size_t)bh * SEQ * DH + (size_t)row * DH + c0;
#pragma unroll
  for (int j = 0; j < 4; ++j) {
    float4 w = {acc[4 * j + 0], acc[4 * j + 1], acc[4 * j + 2], acc[4 * j + 3]};
    *(float4*)&ob[4 * j] = w;
  }
}

// ---------------------------------------------------------------------------
extern "C" void kernel_launch(void* const* d_in, const int* in_sizes, int n_in,
                              void* d_out, int out_size, void* d_ws, size_t ws_size,
                              hipStream_t stream) {
  const float* q = (const float*)d_in[0];
  const float* k = (const float*)d_in[1];
  const float* v = (const float*)d_in[2];
  float* out = (float*)d_out;

  float* kvf = (float*)d_ws;                      // [BH][64*64] = 1 MB
  float* partial = kvf + (size_t)BH * DH * DH;    // [BH*NCHUNK][64*64] = 32 MB

  hipLaunchKernelGGL(kv_partial_kernel, dim3(BH * NCHUNK), dim3(256), 0, stream,
                     k, v, partial);
  hipLaunchKernelGGL(kv_reduce_kernel, dim3(256), dim3(256), 0, stream,
                     partial, kvf);
  hipLaunchKernelGGL(out_kernel, dim3(BH * 64), dim3(256), 0, stream,
                     q, kvf, out);
}

// Round 10
// 76.034 us; speedup vs baseline: 1.4218x; 1.4218x over previous
//
#include <hip/hip_runtime.h>

#define BH  64
#define SEQ 4096
#define DH  64
#define NCHUNK 16
#define CROWS  (SEQ / NCHUNK)   // 256 rows per chunk
#define KSTEPS (CROWS / 32)     // 8 MFMA K-steps per chunk

typedef __attribute__((ext_vector_type(8))) short bf16x8v;  // 8 bf16 (4 VGPR)
typedef __attribute__((ext_vector_type(4))) float f32x4v;   // MFMA acc

// fp32 -> bf16, round-to-nearest-even (bit-exact, no header dependency)
__device__ __forceinline__ short f2bf(float x) {
  unsigned u = __float_as_uint(x);
  return (short)((u + 0x7FFFu + ((u >> 16) & 1u)) >> 16);
}

// ---------------------------------------------------------------------------
// Kernel 1: partial kv = k^T v over a 256-row chunk. One (b,h,chunk)/block.
// 256 threads = 4 waves; wave w owns output quadrant (d0=(w&1)*32,
// e0=(w>>1)*32) as 2x2 MFMA 16x16 tiles -> NO cross-wave reduction.
// MFMA A-frag (k^T) and B-frag (v) are loaded DIRECTLY global->reg:
// lane l reads tensor[s0+(l>>4)*8+j][col0+(l&15)] -- 16-consecutive-float
// 64B segments, coalesced, no LDS, no transpose. fp32->bf16 RNE on the fly.
// 1-step software prefetch. 4 MFMA per K-step per wave.
// ---------------------------------------------------------------------------
__global__ __launch_bounds__(256, 4) void kv_partial_kernel(
    const float* __restrict__ k, const float* __restrict__ v,
    float* __restrict__ partial) {
  const int t = threadIdx.x;
  const int bh = blockIdx.x >> 4;             // / NCHUNK
  const int chunk = blockIdx.x & (NCHUNK - 1);

  const int l  = t & 63;
  const int w  = t >> 6;
  const int lg = l >> 4;     // s-subgroup 0..3
  const int ln = l & 15;     // column within tile
  const int d0 = (w & 1) * 32;
  const int e0 = (w >> 1) * 32;

  const size_t sb = (size_t)bh * SEQ * DH + (size_t)chunk * CROWS * DH;
  const float* kp0 = k + sb + (size_t)(lg * 8) * DH + d0 + ln;       // m-tile 0
  const float* kp1 = kp0 + 16;                                       // m-tile 1
  const float* vp0 = v + sb + (size_t)(lg * 8) * DH + e0 + ln;       // n-tile 0
  const float* vp1 = vp0 + 16;                                       // n-tile 1

  f32x4v acc00 = {0.f, 0.f, 0.f, 0.f};
  f32x4v acc01 = acc00, acc10 = acc00, acc11 = acc00;

  float ck0[8], ck1[8], cv0[8], cv1[8];
#pragma unroll
  for (int j = 0; j < 8; ++j) {
    ck0[j] = kp0[j * DH]; ck1[j] = kp1[j * DH];
    cv0[j] = vp0[j * DH]; cv1[j] = vp1[j * DH];
  }

  for (int ks = 0; ks < KSTEPS; ++ks) {
    float nk0[8], nk1[8], nv0[8], nv1[8];
    if (ks + 1 < KSTEPS) {
      const size_t off = (size_t)(ks + 1) * 32 * DH;
#pragma unroll
      for (int j = 0; j < 8; ++j) {
        nk0[j] = kp0[off + j * DH]; nk1[j] = kp1[off + j * DH];
        nv0[j] = vp0[off + j * DH]; nv1[j] = vp1[off + j * DH];
      }
    }

    bf16x8v a0, a1, b0, b1;
#pragma unroll
    for (int j = 0; j < 8; ++j) {
      a0[j] = f2bf(ck0[j]); a1[j] = f2bf(ck1[j]);
      b0[j] = f2bf(cv0[j]); b1[j] = f2bf(cv1[j]);
    }

    acc00 = __builtin_amdgcn_mfma_f32_16x16x32_bf16(a0, b0, acc00, 0, 0, 0);
    acc01 = __builtin_amdgcn_mfma_f32_16x16x32_bf16(a0, b1, acc01, 0, 0, 0);
    acc10 = __builtin_amdgcn_mfma_f32_16x16x32_bf16(a1, b0, acc10, 0, 0, 0);
    acc11 = __builtin_amdgcn_mfma_f32_16x16x32_bf16(a1, b1, acc11, 0, 0, 0);

    if (ks + 1 < KSTEPS) {
#pragma unroll
      for (int j = 0; j < 8; ++j) {
        ck0[j] = nk0[j]; ck1[j] = nk1[j];
        cv0[j] = nv0[j]; cv1[j] = nv1[j];
      }
    }
  }

  // C/D layout (m89-verified): col = lane&15, row = (lane>>4)*4 + reg
  float* pb = partial + (size_t)blockIdx.x * (DH * DH);
  const int rbase = lg * 4;
#pragma unroll
  for (int r = 0; r < 4; ++r) {
    pb[(d0 +  0 + rbase + r) * 64 + e0 +  0 + ln] = acc00[r];
    pb[(d0 +  0 + rbase + r) * 64 + e0 + 16 + ln] = acc01[r];
    pb[(d0 + 16 + rbase + r) * 64 + e0 +  0 + ln] = acc10[r];
    pb[(d0 + 16 + rbase + r) * 64 + e0 + 16 + ln] = acc11[r];
  }
}

// ---------------------------------------------------------------------------
// Kernel 2: reduce partials -> kvf [BH][64*64]. 256 blocks x 256 threads
// covers 65536 float4 slots.
// ---------------------------------------------------------------------------
__global__ __launch_bounds__(256) void kv_reduce_kernel(
    const float* __restrict__ partial, float* __restrict__ kvf) {
  const int gid = blockIdx.x * 256 + threadIdx.x;
  const int bh = gid >> 10;
  const int idx = gid & 1023;
  float4 s = {0.f, 0.f, 0.f, 0.f};
  for (int c = 0; c < NCHUNK; ++c) {
    const float4* p = (const float4*)(partial + ((size_t)bh * NCHUNK + c) * (DH * DH));
    float4 x = p[idx];
    s.x += x.x; s.y += x.y; s.z += x.z; s.w += x.w;
  }
  ((float4*)kvf)[gid] = s;
}

// ---------------------------------------------------------------------------
// Kernel 3: out = q @ kv. Block = 64 q-rows. Thread = 1 row x 16 cols.
// Entire q row hoisted to registers up front; kv in LDS, broadcast reads.
// ---------------------------------------------------------------------------
__global__ __launch_bounds__(256) void out_kernel(
    const float* __restrict__ q, const float* __restrict__ kvf,
    float* __restrict__ out) {
  const int t = threadIdx.x;
  const int bh = blockIdx.x >> 6;
  const int rb = blockIdx.x & 63;
  const int row = rb * 64 + (t >> 2);
  const int c0 = (t & 3) * 16;

  __shared__ float kv_lds[64 * 64];

  const float4* gkv4 = (const float4*)(kvf + (size_t)bh * (DH * DH));
  float4* kv4 = (float4*)kv_lds;
#pragma unroll
  for (int j = 0; j < 4; ++j) kv4[t + j * 256] = gkv4[t + j * 256];

  const float* qrow = q + (size_t)bh * SEQ * DH + (size_t)row * DH;
  float4 qv[16];
#pragma unroll
  for (int i = 0; i < 16; ++i) qv[i] = *(const float4*)&qrow[i * 4];

  __syncthreads();

  float acc[16];
#pragma unroll
  for (int j = 0; j < 16; ++j) acc[j] = 0.f;

#pragma unroll
  for (int dc = 0; dc < 16; ++dc) {
    float qs[4] = {qv[dc].x, qv[dc].y, qv[dc].z, qv[dc].w};
#pragma unroll
    for (int dd = 0; dd < 4; ++dd) {
      const float* kr = &kv_lds[(dc * 4 + dd) * 64 + c0];
      float4 k0 = *(const float4*)&kr[0];
      float4 k1 = *(const float4*)&kr[4];
      float4 k2 = *(const float4*)&kr[8];
      float4 k3 = *(const float4*)&kr[12];
      const float qsv = qs[dd];
      acc[0]  += qsv * k0.x; acc[1]  += qsv * k0.y;
      acc[2]  += qsv * k0.z; acc[3]  += qsv * k0.w;
      acc[4]  += qsv * k1.x; acc[5]  += qsv * k1.y;
      acc[6]  += qsv * k1.z; acc[7]  += qsv * k1.w;
      acc[8]  += qsv * k2.x; acc[9]  += qsv * k2.y;
      acc[10] += qsv * k2.z; acc[11] += qsv * k2.w;
      acc[12] += qsv * k3.x; acc[13] += qsv * k3.y;
      acc[14] += qsv * k3.z; acc[15] += qsv * k3.w;
    }
  }

  float* ob = out + (size_t)bh * SEQ * DH + (size_t)row * DH + c0;
#pragma unroll
  for (int j = 0; j < 4; ++j) {
    float4 w = {acc[4 * j + 0], acc[4 * j + 1], acc[4 * j + 2], acc[4 * j + 3]};
    *(float4*)&ob[4 * j] = w;
  }
}

// ---------------------------------------------------------------------------
extern "C" void kernel_launch(void* const* d_in, const int* in_sizes, int n_in,
                              void* d_out, int out_size, void* d_ws, size_t ws_size,
                              hipStream_t stream) {
  const float* q = (const float*)d_in[0];
  const float* k = (const float*)d_in[1];
  const float* v = (const float*)d_in[2];
  float* out = (float*)d_out;

  float* kvf = (float*)d_ws;                      // [BH][64*64] = 1 MB
  float* partial = kvf + (size_t)BH * DH * DH;    // [BH*NCHUNK][64*64] = 16 MB

  hipLaunchKernelGGL(kv_partial_kernel, dim3(BH * NCHUNK), dim3(256), 0, stream,
                     k, v, partial);
  hipLaunchKernelGGL(kv_reduce_kernel, dim3(256), dim3(256), 0, stream,
                     partial, kvf);
  hipLaunchKernelGGL(out_kernel, dim3(BH * 64), dim3(256), 0, stream,
                     q, kvf, out);
}